// Round 11
// baseline (908.929 us; speedup 1.0000x reference)
//
#include <hip/hip_runtime.h>

#define FH 128        // feature width (IN == H == 128)
#define CHUNK 1024    // scan chunk
#define RSHIFT 42     // rank field shift in packed histogram
#define WSCALE 4294967296.0f   // 2^32 fixed-point scale for edge weights

typedef unsigned long long u64;
typedef int   i2v __attribute__((ext_vector_type(2)));
typedef float f2v __attribute__((ext_vector_type(2)));

// ---------------- CSR build ----------------

// one packed u64 atomic per edge: low 42 bits = sum(w * 2^32), high bits = count.
// returned old count field = this edge's rank within its dst row.
__device__ __forceinline__ void hist_body(int bid, const int* __restrict__ dst,
                                          const float* __restrict__ w,
                                          u64* hist, unsigned int* __restrict__ rank, int E) {
    int e = bid * 256 + threadIdx.x;
    if (e < E) {
        int d = dst[e];
        u64 inc = ((u64)1 << RSHIFT) | (u64)(w[e] * WSCALE);
        u64 old = atomicAdd(&hist[d], inc);
        rank[e] = (unsigned int)(old >> RSHIFT);
    }
}

// chunk scan of counts + dis/selfn computation fused (one pass over hist)
__global__ __launch_bounds__(256)
void k_scan_dis(const u64* __restrict__ hist, int* __restrict__ rowptr,
                int* __restrict__ bsum, float* __restrict__ dis,
                float* __restrict__ selfn, int N) {
    __shared__ int lds[256];
    int t = threadIdx.x;
    int base = blockIdx.x * CHUNK + t * 4;
    int c0 = 0, c1 = 0, c2 = 0, c3 = 0;
    #pragma unroll
    for (int j = 0; j < 4; ++j) {
        if (base + j < N) {
            u64 p = hist[base + j];
            int c = (int)(p >> RSHIFT);
            float deg = 1.0f + (float)(p & (((u64)1 << RSHIFT) - 1)) * (1.0f / WSCALE);
            float r = rsqrtf(deg);
            dis[base + j]   = r;
            selfn[base + j] = r * r;
            if (j == 0) c0 = c; else if (j == 1) c1 = c; else if (j == 2) c2 = c; else c3 = c;
        }
    }
    int tsum = c0 + c1 + c2 + c3;
    int v = tsum;
    lds[t] = v;
    __syncthreads();
    #pragma unroll
    for (int off = 1; off < 256; off <<= 1) {
        int add = (t >= off) ? lds[t - off] : 0;
        __syncthreads();
        v += add;
        lds[t] = v;
        __syncthreads();
    }
    int ex = v - tsum;  // exclusive prefix of this thread's 4
    if (base + 0 < N) rowptr[base + 0] = ex; ex += c0;
    if (base + 1 < N) rowptr[base + 1] = ex; ex += c1;
    if (base + 2 < N) rowptr[base + 2] = ex; ex += c2;
    if (base + 3 < N) rowptr[base + 3] = ex;
    if (t == 255) bsum[blockIdx.x] = v;     // chunk total
}

// add chunk offsets; each block locally re-scans the <=128 chunk sums
// (folds the old k_scan_blocks launch into this one).
__global__ __launch_bounds__(256)
void k_add_off(int* rowptr, const int* __restrict__ bsum, int N, int E, int NB) {
    __shared__ int incl[128];
    int t = threadIdx.x;
    int x = (t < 128 && t < NB) ? bsum[t] : 0;
    int v = x;
    if (t < 128) incl[t] = v;
    __syncthreads();
    #pragma unroll
    for (int off = 1; off < 128; off <<= 1) {
        int add = (t < 128 && t >= off) ? incl[t - off] : 0;
        __syncthreads();
        if (t < 128) { v += add; incl[t] = v; }
        __syncthreads();
    }
    int i = blockIdx.x * 256 + t;
    if (i < N) {
        int c = i >> 10;
        int off = (c == 0) ? 0 : incl[c - 1];
        rowptr[i] += off;
    }
    if (i == 0) rowptr[N] = E;
}

// no atomic: position = rowptr[dst] + rank (rank captured in hist).
__global__ __launch_bounds__(256)
void k_fill(const int* __restrict__ src, const int* __restrict__ dst,
            const float* __restrict__ w, const unsigned int* __restrict__ rank,
            const float* __restrict__ dis, const int* __restrict__ rowptr,
            i2v* __restrict__ pairs, int E) {
    int e = blockIdx.x * 256 + threadIdx.x;
    if (e < E) {
        int s = src[e], d = dst[e];
        int p = rowptr[d] + (int)rank[e];
        float v = dis[s] * w[e] * dis[d];
        i2v pr; pr.x = s; pr.y = __float_as_int(v);
        __builtin_nontemporal_store(pr, &pairs[p]);
    }
}

// ---------------- dense matmul body: Y = act(X) @ W ----------------
// W (128x128, 64KB) resident in LDS; 32-row X tile staged transposed (16KB).

template<bool RELU>
__device__ __forceinline__ void mm_body(const float* __restrict__ X, const float* __restrict__ W,
                                        float* __restrict__ Y, int nrows, int bid, int nblk) {
    __shared__ float Wl[FH * FH];
    __shared__ float XT[FH][32];
    {
        const float4* W4 = (const float4*)W;
        float4* Wl4 = (float4*)Wl;
        #pragma unroll
        for (int i = 0; i < 16; ++i)
            Wl4[threadIdx.x + 256 * i] = W4[threadIdx.x + 256 * i];
    }
    const int lane = threadIdx.x & 63;
    const int wave = threadIdx.x >> 6;
    const int tr = threadIdx.x >> 3;   // 0..31 : row within tile
    const int tk = threadIdx.x & 7;    // 0..7
    for (int base = bid * 32; base < nrows; base += nblk * 32) {
        __syncthreads();               // protect XT from previous iter's readers
        #pragma unroll
        for (int hh = 0; hh < 4; ++hh) {
            int kg = tk + 8 * hh;      // float4 group 0..31
            float4 v = ((const float4*)X)[(size_t)(base + tr) * 32 + kg];
            if (RELU) {
                v.x = fmaxf(v.x, 0.f); v.y = fmaxf(v.y, 0.f);
                v.z = fmaxf(v.z, 0.f); v.w = fmaxf(v.w, 0.f);
            }
            XT[kg * 4 + 0][tr] = v.x;
            XT[kg * 4 + 1][tr] = v.y;
            XT[kg * 4 + 2][tr] = v.z;
            XT[kg * 4 + 3][tr] = v.w;
        }
        __syncthreads();
        float2 acc[8];
        #pragma unroll
        for (int r = 0; r < 8; ++r) acc[r] = make_float2(0.f, 0.f);
        #pragma unroll 4
        for (int k = 0; k < FH; ++k) {
            float4 xa = *(const float4*)&XT[k][wave * 8];
            float4 xb = *(const float4*)&XT[k][wave * 8 + 4];
            float2 w2 = *(const float2*)&Wl[k * FH + lane * 2];
            acc[0].x = fmaf(xa.x, w2.x, acc[0].x); acc[0].y = fmaf(xa.x, w2.y, acc[0].y);
            acc[1].x = fmaf(xa.y, w2.x, acc[1].x); acc[1].y = fmaf(xa.y, w2.y, acc[1].y);
            acc[2].x = fmaf(xa.z, w2.x, acc[2].x); acc[2].y = fmaf(xa.z, w2.y, acc[2].y);
            acc[3].x = fmaf(xa.w, w2.x, acc[3].x); acc[3].y = fmaf(xa.w, w2.y, acc[3].y);
            acc[4].x = fmaf(xb.x, w2.x, acc[4].x); acc[4].y = fmaf(xb.x, w2.y, acc[4].y);
            acc[5].x = fmaf(xb.y, w2.x, acc[5].x); acc[5].y = fmaf(xb.y, w2.y, acc[5].y);
            acc[6].x = fmaf(xb.z, w2.x, acc[6].x); acc[6].y = fmaf(xb.z, w2.y, acc[6].y);
            acc[7].x = fmaf(xb.w, w2.x, acc[7].x); acc[7].y = fmaf(xb.w, w2.y, acc[7].y);
        }
        #pragma unroll
        for (int r = 0; r < 8; ++r)
            ((float2*)Y)[(size_t)(base + wave * 8 + r) * 64 + lane] = acc[r];
    }
}

template<bool RELU>
__global__ __launch_bounds__(256, 2)
void k_mm(const float* __restrict__ X, const float* __restrict__ W,
          float* __restrict__ Y, int nrows) {
    mm_body<RELU>(X, W, Y, nrows, blockIdx.x, gridDim.x);
}

// fused: blocks [0,mmBlocks) run layer-1 matmul; the rest run the edge histogram.
__global__ __launch_bounds__(256, 2)
void k_mm1_hist(const float* __restrict__ X, const float* __restrict__ W,
                float* __restrict__ Y, int nrows,
                const int* __restrict__ dst, const float* __restrict__ ew,
                u64* hist, unsigned int* __restrict__ rank, int E, int mmBlocks) {
    if ((int)blockIdx.x < mmBlocks)
        mm_body<false>(X, W, Y, nrows, blockIdx.x, mmBlocks);
    else
        hist_body(blockIdx.x - mmBlocks, dst, ew, hist, rank, E);
}

// ---------------- aggregation (feature-split two-pass) ----------------
// Each dispatch handles a 64-column slice: gather working set = 25.6 MB,
// sized to fit aggregate L2 (8 x 4 MB) for a higher hit rate.
// One wave per node: lanes 0-31 even edge slots, 32-63 odd; f2 per lane
// (32 lanes x 8B = 256B half-row, coalesced); 8 gather chains in flight.

template<bool RESID>
__global__ __launch_bounds__(256)
void k_agg(const float* __restrict__ tmp, const int* __restrict__ rowptr,
           const i2v* __restrict__ pairs, const float* __restrict__ selfn,
           const float* __restrict__ bias, const float* __restrict__ ori,
           float* __restrict__ out, int N, int h) {
    int wave = threadIdx.x >> 6, lane = threadIdx.x & 63;
    int row = blockIdx.x * 4 + wave;
    if (row >= N) return;
    const f2v* t2 = (const f2v*)tmp;
    const int ep = lane >> 5;          // edge parity handled by this half-wave
    const int cb = h * 32 + (lane & 31);  // f2 column index within the row
    int start = rowptr[row], end = rowptr[row + 1];
    float ax = 0.f, ay = 0.f;
    int i = start;
    for (; i + 16 <= end; i += 16) {
        #pragma unroll
        for (int k = 0; k < 8; ++k) {
            i2v q = __builtin_nontemporal_load(&pairs[i + 2 * k + ep]);
            f2v t = t2[(size_t)q.x * 64 + cb];
            float v = __int_as_float(q.y);
            ax = fmaf(v, t.x, ax); ay = fmaf(v, t.y, ay);
        }
    }
    for (; i + 8 <= end; i += 8) {
        #pragma unroll
        for (int k = 0; k < 4; ++k) {
            i2v q = __builtin_nontemporal_load(&pairs[i + 2 * k + ep]);
            f2v t = t2[(size_t)q.x * 64 + cb];
            float v = __int_as_float(q.y);
            ax = fmaf(v, t.x, ax); ay = fmaf(v, t.y, ay);
        }
    }
    for (; i + 2 <= end; i += 2) {
        i2v q = __builtin_nontemporal_load(&pairs[i + ep]);
        f2v t = t2[(size_t)q.x * 64 + cb];
        float v = __int_as_float(q.y);
        ax = fmaf(v, t.x, ax); ay = fmaf(v, t.y, ay);
    }
    if (i < end && ep == 0) {          // single leftover edge: even half only
        i2v q = __builtin_nontemporal_load(&pairs[i]);
        f2v t = t2[(size_t)q.x * 64 + cb];
        float v = __int_as_float(q.y);
        ax = fmaf(v, t.x, ax); ay = fmaf(v, t.y, ay);
    }
    // combine even/odd halves (same cb in lanes l and l+32)
    ax += __shfl_xor(ax, 32);
    ay += __shfl_xor(ay, 32);
    if (ep == 0) {
        f2v b2 = ((const f2v*)bias)[cb];
        float sn = selfn[row];
        f2v self = t2[(size_t)row * 64 + cb];
        ax = fmaf(sn, self.x, ax + b2.x);
        ay = fmaf(sn, self.y, ay + b2.y);
        if (RESID) {
            f2v o = __builtin_nontemporal_load(&((const f2v*)ori)[(size_t)row * 64 + cb]);
            ax += o.x; ay += o.y;
        }
        f2v r; r.x = ax; r.y = ay;
        __builtin_nontemporal_store(r, &((f2v*)out)[(size_t)row * 64 + cb]);
    }
}

// ---------------- launch ----------------

extern "C" void kernel_launch(void* const* d_in, const int* in_sizes, int n_in,
                              void* d_out, int out_size, void* d_ws, size_t ws_size,
                              hipStream_t stream) {
    const int*   edge_index = (const int*)d_in[0];
    const float* in_feat    = (const float*)d_in[1];
    const float* ew         = (const float*)d_in[2];
    const float* W1         = (const float*)d_in[3];
    const float* b1         = (const float*)d_in[4];
    const float* W2         = (const float*)d_in[5];
    const float* b2         = (const float*)d_in[6];
    const int E = in_sizes[0] / 2;
    const int N = in_sizes[1] / FH;
    const int* src = edge_index;
    const int* dst = edge_index + E;

    char* ws = (char*)d_ws;
    size_t o = 0;
    auto alloc = [&](size_t bytes) -> void* {
        void* p = ws + o;
        o += (bytes + 255) & ~(size_t)255;
        return p;
    };
    float*        tmp    = (float*)alloc((size_t)N * FH * 4);
    float*        h1     = (float*)alloc((size_t)N * FH * 4);
    i2v*          pairs  = (i2v*)  alloc((size_t)E * 8);
    u64*          hist   = (u64*)  alloc((size_t)N * 8);
    unsigned int* rank   = (unsigned int*)alloc((size_t)E * 4);
    float*        dis    = (float*)alloc((size_t)N * 4);
    float*        selfn  = (float*)alloc((size_t)N * 4);
    int*          rowptr = (int*)  alloc((size_t)(N + 1) * 4);
    int*          bsum   = (int*)  alloc(512);

    int gN = (N + 255) / 256;
    int gE = (E + 255) / 256;
    int NB = (N + CHUNK - 1) / CHUNK;    // 98 <= 128
    const int MMB = 512;                  // mm blocks in the fused launch

    float* out = (float*)d_out;
    int gAgg = (N + 3) / 4;

    (void)hipMemsetAsync(hist, 0, (size_t)N * 8, stream);
    // layer-1 matmul (x @ W1 -> tmp) overlapped with edge histogram
    k_mm1_hist<<<MMB + gE, 256, 0, stream>>>(in_feat, W1, tmp, N,
                                             dst, ew, hist, rank, E, MMB);
    k_scan_dis<<<NB, 256, 0, stream>>>(hist, rowptr, bsum, dis, selfn, N);
    k_add_off<<<gN, 256, 0, stream>>>(rowptr, bsum, N, E, NB);
    k_fill<<<gE, 256, 0, stream>>>(src, dst, ew, rank, dis, rowptr, pairs, E);

    // layer 1 aggregate: h1 = A @ tmp + b1   (two column-half passes)
    k_agg<false><<<gAgg, 256, 0, stream>>>(tmp, rowptr, pairs, selfn, b1, nullptr, h1, N, 0);
    k_agg<false><<<gAgg, 256, 0, stream>>>(tmp, rowptr, pairs, selfn, b1, nullptr, h1, N, 1);
    // layer 2: out = A @ (relu(h1) @ W2) + b2 + h1
    k_mm<true><<<512, 256, 0, stream>>>(h1, W2, tmp, N);
    k_agg<true><<<gAgg, 256, 0, stream>>>(tmp, rowptr, pairs, selfn, b2, h1, out, N, 0);
    k_agg<true><<<gAgg, 256, 0, stream>>>(tmp, rowptr, pairs, selfn, b2, h1, out, N, 1);
    // layer 3: out = A @ (relu(out) @ W2) + b2 + h1
    k_mm<true><<<512, 256, 0, stream>>>(out, W2, tmp, N);
    k_agg<true><<<gAgg, 256, 0, stream>>>(tmp, rowptr, pairs, selfn, b2, h1, out, N, 0);
    k_agg<true><<<gAgg, 256, 0, stream>>>(tmp, rowptr, pairs, selfn, b2, h1, out, N, 1);
}

// Round 12
// 762.820 us; speedup vs baseline: 1.1915x; 1.1915x over previous
//
#include <hip/hip_runtime.h>

#define FH 128        // feature width (IN == H == 128)
#define XTP 36        // XT padded row stride (16B-aligned, 4-way max bank conflict)
#define CHUNK 1024    // scan chunk
#define RSHIFT 42     // rank field shift in packed histogram
#define WSCALE 4294967296.0f   // 2^32 fixed-point scale for edge weights

typedef unsigned long long u64;
typedef int i2v __attribute__((ext_vector_type(2)));

// ---------------- CSR build ----------------

// one packed u64 atomic per edge: low 42 bits = sum(w * 2^32), high bits = count.
// returned old count field = this edge's rank within its dst row.
__device__ __forceinline__ void hist_body(int bid, const int* __restrict__ dst,
                                          const float* __restrict__ w,
                                          u64* hist, unsigned int* __restrict__ rank, int E) {
    int e = bid * 256 + threadIdx.x;
    if (e < E) {
        int d = dst[e];
        u64 inc = ((u64)1 << RSHIFT) | (u64)(w[e] * WSCALE);
        u64 old = atomicAdd(&hist[d], inc);
        rank[e] = (unsigned int)(old >> RSHIFT);
    }
}

// chunk scan of counts + dis/selfn computation fused (one pass over hist)
__global__ __launch_bounds__(256)
void k_scan_dis(const u64* __restrict__ hist, int* __restrict__ rowptr,
                int* __restrict__ bsum, float* __restrict__ dis,
                float* __restrict__ selfn, int N) {
    __shared__ int lds[256];
    int t = threadIdx.x;
    int base = blockIdx.x * CHUNK + t * 4;
    int c0 = 0, c1 = 0, c2 = 0, c3 = 0;
    #pragma unroll
    for (int j = 0; j < 4; ++j) {
        if (base + j < N) {
            u64 p = hist[base + j];
            int c = (int)(p >> RSHIFT);
            float deg = 1.0f + (float)(p & (((u64)1 << RSHIFT) - 1)) * (1.0f / WSCALE);
            float r = rsqrtf(deg);
            dis[base + j]   = r;
            selfn[base + j] = r * r;
            if (j == 0) c0 = c; else if (j == 1) c1 = c; else if (j == 2) c2 = c; else c3 = c;
        }
    }
    int tsum = c0 + c1 + c2 + c3;
    int v = tsum;
    lds[t] = v;
    __syncthreads();
    #pragma unroll
    for (int off = 1; off < 256; off <<= 1) {
        int add = (t >= off) ? lds[t - off] : 0;
        __syncthreads();
        v += add;
        lds[t] = v;
        __syncthreads();
    }
    int ex = v - tsum;  // exclusive prefix of this thread's 4
    if (base + 0 < N) rowptr[base + 0] = ex; ex += c0;
    if (base + 1 < N) rowptr[base + 1] = ex; ex += c1;
    if (base + 2 < N) rowptr[base + 2] = ex; ex += c2;
    if (base + 3 < N) rowptr[base + 3] = ex;
    if (t == 255) bsum[blockIdx.x] = v;     // chunk total
}

// add chunk offsets; each block locally re-scans the <=128 chunk sums.
__global__ __launch_bounds__(256)
void k_add_off(int* rowptr, const int* __restrict__ bsum, int N, int E, int NB) {
    __shared__ int incl[128];
    int t = threadIdx.x;
    int x = (t < 128 && t < NB) ? bsum[t] : 0;
    int v = x;
    if (t < 128) incl[t] = v;
    __syncthreads();
    #pragma unroll
    for (int off = 1; off < 128; off <<= 1) {
        int add = (t < 128 && t >= off) ? incl[t - off] : 0;
        __syncthreads();
        if (t < 128) { v += add; incl[t] = v; }
        __syncthreads();
    }
    int i = blockIdx.x * 256 + t;
    if (i < N) {
        int c = i >> 10;
        int off = (c == 0) ? 0 : incl[c - 1];
        rowptr[i] += off;
    }
    if (i == 0) rowptr[N] = E;
}

// no atomic: position = rowptr[dst] + rank (rank captured in hist).
__global__ __launch_bounds__(256)
void k_fill(const int* __restrict__ src, const int* __restrict__ dst,
            const float* __restrict__ w, const unsigned int* __restrict__ rank,
            const float* __restrict__ dis, const int* __restrict__ rowptr,
            i2v* __restrict__ pairs, int E) {
    int e = blockIdx.x * 256 + threadIdx.x;
    if (e < E) {
        int s = src[e], d = dst[e];
        int p = rowptr[d] + (int)rank[e];
        float v = dis[s] * w[e] * dis[d];
        i2v pr; pr.x = s; pr.y = __float_as_int(v);
        __builtin_nontemporal_store(pr, &pairs[p]);
    }
}

// ---------------- dense matmul body: Y = act(X) @ W ----------------
// W read directly from global (64 KB, L1/L2-resident, shared by all blocks).
// Only the 32-row X tile is staged in LDS (transposed, padded) -> 18.4 KB,
// occupancy no longer LDS-capped (was 80 KB -> 2 blocks/CU, 20.7% occ).

template<bool RELU>
__device__ __forceinline__ void mm_body(const float* __restrict__ X, const float* __restrict__ W,
                                        float* __restrict__ Y, int nrows, int bid, int nblk) {
    __shared__ float XT[FH][XTP];
    const int lane = threadIdx.x & 63;
    const int wave = threadIdx.x >> 6;
    const int tr = threadIdx.x >> 3;   // 0..31 : row within tile
    const int tk = threadIdx.x & 7;    // 0..7
    for (int base = bid * 32; base < nrows; base += nblk * 32) {
        __syncthreads();               // protect XT from previous iter's readers
        #pragma unroll
        for (int hh = 0; hh < 4; ++hh) {
            int kg = tk + 8 * hh;      // float4 group 0..31
            float4 v = ((const float4*)X)[(size_t)(base + tr) * 32 + kg];
            if (RELU) {
                v.x = fmaxf(v.x, 0.f); v.y = fmaxf(v.y, 0.f);
                v.z = fmaxf(v.z, 0.f); v.w = fmaxf(v.w, 0.f);
            }
            XT[kg * 4 + 0][tr] = v.x;
            XT[kg * 4 + 1][tr] = v.y;
            XT[kg * 4 + 2][tr] = v.z;
            XT[kg * 4 + 3][tr] = v.w;
        }
        __syncthreads();
        float2 acc[8];
        #pragma unroll
        for (int r = 0; r < 8; ++r) acc[r] = make_float2(0.f, 0.f);
        #pragma unroll 4
        for (int k = 0; k < FH; ++k) {
            float4 xa = *(const float4*)&XT[k][wave * 8];
            float4 xb = *(const float4*)&XT[k][wave * 8 + 4];
            float2 w2 = *(const float2*)&W[k * FH + lane * 2];   // global, cached
            acc[0].x = fmaf(xa.x, w2.x, acc[0].x); acc[0].y = fmaf(xa.x, w2.y, acc[0].y);
            acc[1].x = fmaf(xa.y, w2.x, acc[1].x); acc[1].y = fmaf(xa.y, w2.y, acc[1].y);
            acc[2].x = fmaf(xa.z, w2.x, acc[2].x); acc[2].y = fmaf(xa.z, w2.y, acc[2].y);
            acc[3].x = fmaf(xa.w, w2.x, acc[3].x); acc[3].y = fmaf(xa.w, w2.y, acc[3].y);
            acc[4].x = fmaf(xb.x, w2.x, acc[4].x); acc[4].y = fmaf(xb.x, w2.y, acc[4].y);
            acc[5].x = fmaf(xb.y, w2.x, acc[5].x); acc[5].y = fmaf(xb.y, w2.y, acc[5].y);
            acc[6].x = fmaf(xb.z, w2.x, acc[6].x); acc[6].y = fmaf(xb.z, w2.y, acc[6].y);
            acc[7].x = fmaf(xb.w, w2.x, acc[7].x); acc[7].y = fmaf(xb.w, w2.y, acc[7].y);
        }
        #pragma unroll
        for (int r = 0; r < 8; ++r)
            ((float2*)Y)[(size_t)(base + wave * 8 + r) * 64 + lane] = acc[r];
    }
}

template<bool RELU>
__global__ __launch_bounds__(256)
void k_mm(const float* __restrict__ X, const float* __restrict__ W,
          float* __restrict__ Y, int nrows) {
    mm_body<RELU>(X, W, Y, nrows, blockIdx.x, gridDim.x);
}

// fused: blocks [0,mmBlocks) run layer-1 matmul; the rest run the edge histogram.
__global__ __launch_bounds__(256)
void k_mm1_hist(const float* __restrict__ X, const float* __restrict__ W,
                float* __restrict__ Y, int nrows,
                const int* __restrict__ dst, const float* __restrict__ ew,
                u64* hist, unsigned int* __restrict__ rank, int E, int mmBlocks) {
    if ((int)blockIdx.x < mmBlocks)
        mm_body<false>(X, W, Y, nrows, blockIdx.x, mmBlocks);
    else
        hist_body(blockIdx.x - mmBlocks, dst, ew, hist, rank, E);
}

// ---------------- aggregation (round-6 measured-best structure) ----------------
// out[i] = selfn[i]*tmp[i] + sum_e val*tmp[col] + b (+ ori)
// one wave per node; lane holds float2 of the 128-wide row; 4x unrolled gathers.
// VGPR 20, occupancy ~77%, 3.86 TB/s beyond-L2 = the L3 gather ceiling.

template<bool RESID>
__global__ __launch_bounds__(256)
void k_agg(const float* __restrict__ tmp, const int* __restrict__ rowptr,
           const i2v* __restrict__ pairs, const float* __restrict__ selfn,
           const float* __restrict__ bias, const float* __restrict__ ori,
           float* __restrict__ out, int N) {
    int wave = threadIdx.x >> 6, lane = threadIdx.x & 63;
    int row = blockIdx.x * 4 + wave;
    if (row >= N) return;
    const float2* t2 = (const float2*)tmp;
    int start = rowptr[row], end = rowptr[row + 1];
    float2 b2 = ((const float2*)bias)[lane];
    float sn = selfn[row];
    float2 self = t2[(size_t)row * 64 + lane];
    float ax = fmaf(sn, self.x, b2.x);
    float ay = fmaf(sn, self.y, b2.y);
    int e = start;
    for (; e + 4 <= end; e += 4) {
        i2v q0 = pairs[e], q1 = pairs[e + 1], q2 = pairs[e + 2], q3 = pairs[e + 3];
        float2 t0 = t2[(size_t)q0.x * 64 + lane];
        float2 t1 = t2[(size_t)q1.x * 64 + lane];
        float2 t2v = t2[(size_t)q2.x * 64 + lane];
        float2 t3 = t2[(size_t)q3.x * 64 + lane];
        float v0 = __int_as_float(q0.y), v1 = __int_as_float(q1.y);
        float v2 = __int_as_float(q2.y), v3 = __int_as_float(q3.y);
        ax = fmaf(v0, t0.x, ax); ay = fmaf(v0, t0.y, ay);
        ax = fmaf(v1, t1.x, ax); ay = fmaf(v1, t1.y, ay);
        ax = fmaf(v2, t2v.x, ax); ay = fmaf(v2, t2v.y, ay);
        ax = fmaf(v3, t3.x, ax); ay = fmaf(v3, t3.y, ay);
    }
    for (; e < end; ++e) {
        i2v q0 = pairs[e];
        float2 t0 = t2[(size_t)q0.x * 64 + lane];
        float v0 = __int_as_float(q0.y);
        ax = fmaf(v0, t0.x, ax); ay = fmaf(v0, t0.y, ay);
    }
    if (RESID) {
        float2 o = ((const float2*)ori)[(size_t)row * 64 + lane];
        ax += o.x; ay += o.y;
    }
    float2 r; r.x = ax; r.y = ay;
    ((float2*)out)[(size_t)row * 64 + lane] = r;
}

// ---------------- launch ----------------

extern "C" void kernel_launch(void* const* d_in, const int* in_sizes, int n_in,
                              void* d_out, int out_size, void* d_ws, size_t ws_size,
                              hipStream_t stream) {
    const int*   edge_index = (const int*)d_in[0];
    const float* in_feat    = (const float*)d_in[1];
    const float* ew         = (const float*)d_in[2];
    const float* W1         = (const float*)d_in[3];
    const float* b1         = (const float*)d_in[4];
    const float* W2         = (const float*)d_in[5];
    const float* b2         = (const float*)d_in[6];
    const int E = in_sizes[0] / 2;
    const int N = in_sizes[1] / FH;
    const int* src = edge_index;
    const int* dst = edge_index + E;

    char* ws = (char*)d_ws;
    size_t o = 0;
    auto alloc = [&](size_t bytes) -> void* {
        void* p = ws + o;
        o += (bytes + 255) & ~(size_t)255;
        return p;
    };
    float*        tmp    = (float*)alloc((size_t)N * FH * 4);
    float*        h1     = (float*)alloc((size_t)N * FH * 4);
    i2v*          pairs  = (i2v*)  alloc((size_t)E * 8);
    u64*          hist   = (u64*)  alloc((size_t)N * 8);
    unsigned int* rank   = (unsigned int*)alloc((size_t)E * 4);
    float*        dis    = (float*)alloc((size_t)N * 4);
    float*        selfn  = (float*)alloc((size_t)N * 4);
    int*          rowptr = (int*)  alloc((size_t)(N + 1) * 4);
    int*          bsum   = (int*)  alloc(512);

    int gN = (N + 255) / 256;
    int gE = (E + 255) / 256;
    int NB = (N + CHUNK - 1) / CHUNK;    // 98 <= 128
    int gMM = (N + 31) / 32;             // one 32-row tile per block
    const int MMB = 1024;                // mm blocks inside the fused launch

    float* out = (float*)d_out;
    int gAgg = (N + 3) / 4;

    (void)hipMemsetAsync(hist, 0, (size_t)N * 8, stream);
    // layer-1 matmul (x @ W1 -> tmp) overlapped with edge histogram
    k_mm1_hist<<<MMB + gE, 256, 0, stream>>>(in_feat, W1, tmp, N,
                                             dst, ew, hist, rank, E, MMB);
    k_scan_dis<<<NB, 256, 0, stream>>>(hist, rowptr, bsum, dis, selfn, N);
    k_add_off<<<gN, 256, 0, stream>>>(rowptr, bsum, N, E, NB);
    k_fill<<<gE, 256, 0, stream>>>(src, dst, ew, rank, dis, rowptr, pairs, E);

    // layer 1 aggregate: h1 = A @ tmp + b1
    k_agg<false><<<gAgg, 256, 0, stream>>>(tmp, rowptr, pairs, selfn, b1, nullptr, h1, N);
    // layer 2: out = A @ (relu(h1) @ W2) + b2 + h1
    k_mm<true><<<gMM, 256, 0, stream>>>(h1, W2, tmp, N);
    k_agg<true><<<gAgg, 256, 0, stream>>>(tmp, rowptr, pairs, selfn, b2, h1, out, N);
    // layer 3: out = A @ (relu(out) @ W2) + b2 + h1
    k_mm<true><<<gMM, 256, 0, stream>>>(out, W2, tmp, N);
    k_agg<true><<<gAgg, 256, 0, stream>>>(tmp, rowptr, pairs, selfn, b2, h1, out, N);
}